// Round 1
// baseline (2068.630 us; speedup 1.0000x reference)
//
#include <hip/hip_runtime.h>
#include <math.h>

#define NN 50000
#define NE 800000
#define NG 512
#define NET (NE + NN)   // edges + self loops

__device__ __forceinline__ float wsum64(float v) {
#pragma unroll
    for (int o = 32; o > 0; o >>= 1) v += __shfl_down(v, o, 64);
    return v;
}

__device__ __forceinline__ void atomicMaxF(float* a, float v) {
    if (v >= 0.f) atomicMax((int*)a, __float_as_int(v));
    else atomicMin((unsigned int*)a, __float_as_uint(v));
}

// A = x @ W_gat  ([NN,9]@[9,64]); alpha_s = A@a_src, alpha_d = A@a_dst
__global__ void k_gat_input(const float* __restrict__ x, const float* __restrict__ Wg,
                            const float* __restrict__ avs, const float* __restrict__ avd,
                            float* __restrict__ A, float* __restrict__ als, float* __restrict__ ald) {
    __shared__ float sW[9 * 64];
    __shared__ float sas[64], sad[64];
    int t = threadIdx.x;
    for (int i = t; i < 9 * 64; i += 256) sW[i] = Wg[i];
    if (t < 64) { sas[t] = avs[t]; sad[t] = avd[t]; }
    __syncthreads();
    int node = blockIdx.x * 4 + (t >> 6);
    int u = t & 63;
    if (node >= NN) return;
    float h = 0.f;
#pragma unroll
    for (int f = 0; f < 9; f++) h += x[node * 9 + f] * sW[f * 64 + u];
    A[node * 64 + u] = h;
    float ps = wsum64(h * sas[u]);
    float pd = wsum64(h * sad[u]);
    if (u == 0) { als[node] = ps; ald[node] = pd; }
}

// B[i,u] = bias[u]; m=-inf; denom=0; deg=0
__global__ void k_init_gat(float* __restrict__ B, const float* __restrict__ bias,
                           float* __restrict__ m, float* __restrict__ den, float* __restrict__ deg) {
    int i = blockIdx.x * 256 + threadIdx.x;
    if (i < NN * 64) B[i] = bias[i & 63];
    if (i < NN) { m[i] = -INFINITY; den[i] = 0.f; deg[i] = 0.f; }
}

__global__ void k_init_bias(float* __restrict__ B, const float* __restrict__ bias) {
    int i = blockIdx.x * 256 + threadIdx.x;
    if (i < NN * 64) B[i] = bias[i & 63];
}

// pass 1: segment max of leaky_relu(as[src]+ad[dst]) over dst; also deg count
__global__ void k_edge_p1(const int* __restrict__ ei, const float* __restrict__ als,
                          const float* __restrict__ ald, float* __restrict__ m, float* __restrict__ deg) {
    int e = blockIdx.x * 256 + threadIdx.x;
    if (e >= NET) return;
    int s, d;
    if (e < NE) { s = ei[e]; d = ei[NE + e]; } else { s = d = e - NE; }
    float v = als[s] + ald[d];
    v = v >= 0.f ? v : 0.2f * v;
    atomicMaxF(&m[d], v);
    atomicAdd(&deg[d], 1.f);
}

// pass 2: denom[dst] += exp(e - m[dst])
__global__ void k_edge_p2(const int* __restrict__ ei, const float* __restrict__ als,
                          const float* __restrict__ ald, const float* __restrict__ m,
                          float* __restrict__ den) {
    int e = blockIdx.x * 256 + threadIdx.x;
    if (e >= NET) return;
    int s, d;
    if (e < NE) { s = ei[e]; d = ei[NE + e]; } else { s = d = e - NE; }
    float v = als[s] + ald[d];
    v = v >= 0.f ? v : 0.2f * v;
    atomicAdd(&den[d], expf(v - m[d]));
}

// pass 3: B[dst] += A[src] * coef   (wave per edge, lane = feature)
__global__ void k_gat_aggr(const int* __restrict__ ei, const float* __restrict__ als,
                           const float* __restrict__ ald, const float* __restrict__ m,
                           const float* __restrict__ den, const float* __restrict__ A,
                           float* __restrict__ B) {
    int e = blockIdx.x * 4 + (threadIdx.x >> 6);
    int u = threadIdx.x & 63;
    if (e >= NET) return;
    int s = 0, d = 0;
    float coef = 0.f;
    if (u == 0) {
        if (e < NE) { s = ei[e]; d = ei[NE + e]; } else { s = d = e - NE; }
        float v = als[s] + ald[d];
        v = v >= 0.f ? v : 0.2f * v;
        coef = expf(v - m[d]) / den[d];
    }
    s = __shfl(s, 0, 64); d = __shfl(d, 0, 64); coef = __shfl(coef, 0, 64);
    atomicAdd(&B[d * 64 + u], A[s * 64 + u] * coef);
}

// GCN aggregation: B[dst] += A[src] * dinv[src]*dinv[dst]
__global__ void k_gcn_aggr(const int* __restrict__ ei, const float* __restrict__ dinv,
                           const float* __restrict__ A, float* __restrict__ B) {
    int e = blockIdx.x * 4 + (threadIdx.x >> 6);
    int u = threadIdx.x & 63;
    if (e >= NET) return;
    int s = 0, d = 0;
    float w = 0.f;
    if (u == 0) {
        if (e < NE) { s = ei[e]; d = ei[NE + e]; } else { s = d = e - NE; }
        w = dinv[s] * dinv[d];
    }
    s = __shfl(s, 0, 64); d = __shfl(d, 0, 64); w = __shfl(w, 0, 64);
    atomicAdd(&B[d * 64 + u], A[s * 64 + u] * w);
}

__global__ void k_tanh(float* __restrict__ B, int n) {
    int i = blockIdx.x * 256 + threadIdx.x;
    if (i < n) B[i] = tanhf(B[i]);
}

__global__ void k_rsqrt(float* __restrict__ d) {
    int i = blockIdx.x * 256 + threadIdx.x;
    if (i < NN) { float v = d[i]; d[i] = v > 0.f ? rsqrtf(v) : 0.f; }
}

// Y = X @ W  ([NN,64]@[64,64]), W in LDS, 4 nodes/block
__global__ void k_lin64(const float* __restrict__ X, const float* __restrict__ W,
                        float* __restrict__ Y) {
    __shared__ float sW[64 * 64];
    __shared__ float sX[4 * 64];
    int t = threadIdx.x;
    for (int i = t; i < 64 * 64; i += 256) sW[i] = W[i];
    int r = t >> 6, u = t & 63;
    int node = blockIdx.x * 4 + r;
    sX[t] = node < NN ? X[node * 64 + u] : 0.f;
    __syncthreads();
    if (node >= NN) return;
    float acc = 0.f;
#pragma unroll
    for (int k = 0; k < 64; k++) acc += sX[r * 64 + k] * sW[k * 64 + u];
    Y[node * 64 + u] = acc;
}

// MLP (64->64 tanh ->32 tanh ->1) + mean-pool accumulation
__global__ void k_mlp_pool(const float* __restrict__ X, const int* __restrict__ batch,
                           const float* __restrict__ W1, const float* __restrict__ b1,
                           const float* __restrict__ W2, const float* __restrict__ b2,
                           const float* __restrict__ W3, const float* __restrict__ b3,
                           float* __restrict__ sums, float* __restrict__ cnts) {
    __shared__ float sW1[64 * 64];
    __shared__ float sW2[64 * 32];
    __shared__ float sW3[32], sb1[64], sb2[32];
    __shared__ float sX[4 * 64];
    __shared__ float sY1[4 * 64];
    __shared__ float sY2[4 * 32];
    int t = threadIdx.x;
    for (int i = t; i < 64 * 64; i += 256) sW1[i] = W1[i];
    for (int i = t; i < 64 * 32; i += 256) sW2[i] = W2[i];
    if (t < 32) { sW3[t] = W3[t]; sb2[t] = b2[t]; }
    if (t < 64) sb1[t] = b1[t];
    int r = t >> 6, u = t & 63;
    int node = blockIdx.x * 4 + r;
    sX[t] = node < NN ? X[node * 64 + u] : 0.f;
    __syncthreads();
    float acc = sb1[u];
#pragma unroll
    for (int k = 0; k < 64; k++) acc += sX[r * 64 + k] * sW1[k * 64 + u];
    sY1[t] = tanhf(acc);
    __syncthreads();
    if (u < 32) {
        float a2 = sb2[u];
#pragma unroll
        for (int k = 0; k < 64; k++) a2 += sY1[r * 64 + k] * sW2[k * 32 + u];
        sY2[r * 32 + u] = tanhf(a2);
    }
    __syncthreads();
    float p = (u < 32) ? sY2[r * 32 + u] * sW3[u] : 0.f;
    p = wsum64(p);
    if (u == 0 && node < NN) {
        float v = p + b3[0];
        int g = batch[node];
        atomicAdd(&sums[g], v);
        atomicAdd(&cnts[g], 1.f);
    }
}

__global__ void k_zero(float* __restrict__ p, int n) {
    int i = blockIdx.x * 256 + threadIdx.x;
    if (i < n) p[i] = 0.f;
}

// pool layout: [sa(NG), ca(NG), sb(NG), cb(NG)]
__global__ void k_final(const float* __restrict__ pool, float* __restrict__ out) {
    int g = blockIdx.x * 256 + threadIdx.x;
    if (g >= NG) return;
    float ua = pool[g] / fmaxf(pool[NG + g], 1.f);
    float ub = pool[2 * NG + g] / fmaxf(pool[3 * NG + g], 1.f);
    float z = ub - ua;
    out[g] = 1.f / (1.f + expf(-z));
}

struct Params {
    const float *Wg, *avs, *avd, *bg, *Wgcn, *bgcn, *W1, *b1, *W2, *b2, *W3, *b3;
};

static void run_branch(const float* x, const int* ei, const int* batch, const Params& P,
                       float* A, float* B, float* als, float* ald, float* m, float* den,
                       float* dinv, float* psum, float* pcnt, hipStream_t st) {
    dim3 blk(256);
    const int gNode4 = (NN + 3) / 4;          // 4 nodes / block
    const int gNF = (NN * 64 + 255) / 256;    // elementwise over node features
    const int gE = (NET + 255) / 256;         // 1 thread / edge
    const int gE4 = (NET + 3) / 4;            // 1 wave / edge

    k_gat_input<<<gNode4, blk, 0, st>>>(x, P.Wg, P.avs, P.avd, A, als, ald);
    k_init_gat<<<gNF, blk, 0, st>>>(B, P.bg, m, den, dinv);
    k_edge_p1<<<gE, blk, 0, st>>>(ei, als, ald, m, dinv);
    k_edge_p2<<<gE, blk, 0, st>>>(ei, als, ald, m, den);
    k_gat_aggr<<<gE4, blk, 0, st>>>(ei, als, ald, m, den, A, B);
    k_tanh<<<gNF, blk, 0, st>>>(B, NN * 64);
    k_rsqrt<<<(NN + 255) / 256, blk, 0, st>>>(dinv);
    for (int l = 0; l < 2; l++) {
        k_lin64<<<gNode4, blk, 0, st>>>(B, P.Wgcn + l * 64 * 64, A);
        k_init_bias<<<gNF, blk, 0, st>>>(B, P.bgcn + l * 64);
        k_gcn_aggr<<<gE4, blk, 0, st>>>(ei, dinv, A, B);
        k_tanh<<<gNF, blk, 0, st>>>(B, NN * 64);
    }
    k_mlp_pool<<<gNode4, blk, 0, st>>>(B, batch, P.W1, P.b1, P.W2, P.b2, P.W3, P.b3,
                                       psum, pcnt);
}

extern "C" void kernel_launch(void* const* d_in, const int* in_sizes, int n_in,
                              void* d_out, int out_size, void* d_ws, size_t ws_size,
                              hipStream_t stream) {
    const float* x_a = (const float*)d_in[0];
    const float* x_b = (const float*)d_in[1];
    const int* ei_a = (const int*)d_in[2];
    const int* ei_b = (const int*)d_in[3];
    const int* batch_a = (const int*)d_in[4];
    const int* batch_b = (const int*)d_in[5];
    Params P;
    P.Wg  = (const float*)d_in[6];
    P.avs = (const float*)d_in[7];
    P.avd = (const float*)d_in[8];
    P.bg  = (const float*)d_in[9];
    P.Wgcn = (const float*)d_in[10];
    P.bgcn = (const float*)d_in[11];
    P.W1 = (const float*)d_in[12];
    P.b1 = (const float*)d_in[13];
    P.W2 = (const float*)d_in[14];
    P.b2 = (const float*)d_in[15];
    P.W3 = (const float*)d_in[16];
    P.b3 = (const float*)d_in[17];

    float* ws = (float*)d_ws;
    float* A    = ws;                 // NN*64
    float* B    = A + NN * 64;        // NN*64
    float* als  = B + NN * 64;        // NN
    float* ald  = als + NN;           // NN
    float* m    = ald + NN;           // NN
    float* den  = m + NN;             // NN
    float* dinv = den + NN;           // NN (deg -> rsqrt)
    float* pool = dinv + NN;          // 4*NG: sa, ca, sb, cb

    k_zero<<<(4 * NG + 255) / 256, 256, 0, stream>>>(pool, 4 * NG);
    run_branch(x_a, ei_a, batch_a, P, A, B, als, ald, m, den, dinv,
               pool, pool + NG, stream);
    run_branch(x_b, ei_b, batch_b, P, A, B, als, ald, m, den, dinv,
               pool + 2 * NG, pool + 3 * NG, stream);
    k_final<<<(NG + 255) / 256, 256, 0, stream>>>(pool, (float*)d_out);
}

// Round 2
// 1435.608 us; speedup vs baseline: 1.4409x; 1.4409x over previous
//
#include <hip/hip_runtime.h>
#include <math.h>

#define NN 50000
#define NE 800000
#define NG 512
#define NET (NE + NN)   // edges + self loops

__device__ __forceinline__ float wsum64(float v) {
#pragma unroll
    for (int o = 32; o > 0; o >>= 1) v += __shfl_down(v, o, 64);
    return v;
}

// ---------------- CSR build ----------------

__global__ void k_zero_i(int* __restrict__ p, int n) {
    int i = blockIdx.x * 256 + threadIdx.x;
    if (i < n) p[i] = 0;
}

__global__ void k_deg(const int* __restrict__ ei, int* __restrict__ cnt) {
    int e = blockIdx.x * 256 + threadIdx.x;
    if (e >= NET) return;
    int d = (e < NE) ? ei[NE + e] : (e - NE);
    atomicAdd(&cnt[d], 1);
}

// exclusive scan of cnt[NN] -> rowptr[NN+1], cursor[NN] (single block, 1024 thr)
__global__ void k_scan(const int* __restrict__ cnt, int* __restrict__ rowptr,
                       int* __restrict__ cursor) {
    __shared__ int s[1024];
    __shared__ int carry;
    int t = threadIdx.x;
    if (t == 0) carry = 0;
    __syncthreads();
    for (int base = 0; base < NN; base += 1024) {
        int i = base + t;
        int v = (i < NN) ? cnt[i] : 0;
        s[t] = v;
        __syncthreads();
        for (int o = 1; o < 1024; o <<= 1) {
            int add = (t >= o) ? s[t - o] : 0;
            __syncthreads();
            s[t] += add;
            __syncthreads();
        }
        int excl = s[t] - v + carry;
        if (i < NN) { rowptr[i] = excl; cursor[i] = excl; }
        __syncthreads();
        if (t == 1023) carry += s[1023];
        __syncthreads();
    }
    if (t == 0) rowptr[NN] = carry;
}

__global__ void k_scatter(const int* __restrict__ ei, int* __restrict__ cursor,
                          int* __restrict__ csr_src) {
    int e = blockIdx.x * 256 + threadIdx.x;
    if (e >= NET) return;
    int s, d;
    if (e < NE) { s = ei[e]; d = ei[NE + e]; } else { s = d = e - NE; }
    int pos = atomicAdd(&cursor[d], 1);
    csr_src[pos] = s;
}

__global__ void k_dinv(const int* __restrict__ rowptr, float* __restrict__ dinv) {
    int i = blockIdx.x * 256 + threadIdx.x;
    if (i < NN) {
        int dg = rowptr[i + 1] - rowptr[i];
        dinv[i] = dg > 0 ? rsqrtf((float)dg) : 0.f;
    }
}

// ---------------- node-level kernels ----------------

// A = x @ W_gat  ([NN,9]@[9,64]); alpha_s = A@a_src, alpha_d = A@a_dst
__global__ void k_gat_input(const float* __restrict__ x, const float* __restrict__ Wg,
                            const float* __restrict__ avs, const float* __restrict__ avd,
                            float* __restrict__ A, float* __restrict__ als, float* __restrict__ ald) {
    __shared__ float sW[9 * 64];
    __shared__ float sas[64], sad[64];
    int t = threadIdx.x;
    for (int i = t; i < 9 * 64; i += 256) sW[i] = Wg[i];
    if (t < 64) { sas[t] = avs[t]; sad[t] = avd[t]; }
    __syncthreads();
    int node = blockIdx.x * 4 + (t >> 6);
    int u = t & 63;
    if (node >= NN) return;
    float h = 0.f;
#pragma unroll
    for (int f = 0; f < 9; f++) h += x[node * 9 + f] * sW[f * 64 + u];
    A[node * 64 + u] = h;
    float ps = wsum64(h * sas[u]);
    float pd = wsum64(h * sad[u]);
    if (u == 0) { als[node] = ps; ald[node] = pd; }
}

// GAT: per-dst wave; softmax over incoming edges + aggregate + bias + tanh
__global__ void k_gat_csr(const int* __restrict__ rowptr, const int* __restrict__ csr_src,
                          const float* __restrict__ als, const float* __restrict__ ald,
                          const float* __restrict__ A, const float* __restrict__ bias,
                          float* __restrict__ B) {
    int d = blockIdx.x * 4 + (threadIdx.x >> 6);
    int u = threadIdx.x & 63;
    if (d >= NN) return;
    int beg = rowptr[d], end = rowptr[d + 1];
    float ad = ald[d];
    // max over edges (lanes parallel over edges)
    float mx = -INFINITY;
    for (int i = beg + u; i < end; i += 64) {
        float v = als[csr_src[i]] + ad;
        v = v >= 0.f ? v : 0.2f * v;
        mx = fmaxf(mx, v);
    }
#pragma unroll
    for (int o = 32; o > 0; o >>= 1) mx = fmaxf(mx, __shfl_down(mx, o, 64));
    mx = __shfl(mx, 0, 64);
    // exp-sum
    float sm = 0.f;
    for (int i = beg + u; i < end; i += 64) {
        float v = als[csr_src[i]] + ad;
        v = v >= 0.f ? v : 0.2f * v;
        sm += expf(v - mx);
    }
    sm = wsum64(sm);
    sm = __shfl(sm, 0, 64);
    float inv = 1.f / sm;
    // aggregate (lanes parallel over features)
    float acc = bias[u];
    for (int i = beg; i < end; i++) {
        int s = csr_src[i];
        float v = als[s] + ad;
        v = v >= 0.f ? v : 0.2f * v;
        acc += A[s * 64 + u] * (expf(v - mx) * inv);
    }
    B[d * 64 + u] = tanhf(acc);
}

// GCN: per-dst wave; aggregate + bias + tanh
__global__ void k_gcn_csr(const int* __restrict__ rowptr, const int* __restrict__ csr_src,
                          const float* __restrict__ dinv, const float* __restrict__ A,
                          const float* __restrict__ bias, float* __restrict__ B) {
    int d = blockIdx.x * 4 + (threadIdx.x >> 6);
    int u = threadIdx.x & 63;
    if (d >= NN) return;
    int beg = rowptr[d], end = rowptr[d + 1];
    float dd = dinv[d];
    float acc = bias[u];
    for (int i = beg; i < end; i++) {
        int s = csr_src[i];
        acc += A[s * 64 + u] * (dinv[s] * dd);
    }
    B[d * 64 + u] = tanhf(acc);
}

// Y = X @ W  ([NN,64]@[64,64]), W in LDS, 4 nodes/block
__global__ void k_lin64(const float* __restrict__ X, const float* __restrict__ W,
                        float* __restrict__ Y) {
    __shared__ float sW[64 * 64];
    __shared__ float sX[4 * 64];
    int t = threadIdx.x;
    for (int i = t; i < 64 * 64; i += 256) sW[i] = W[i];
    int r = t >> 6, u = t & 63;
    int node = blockIdx.x * 4 + r;
    sX[t] = node < NN ? X[node * 64 + u] : 0.f;
    __syncthreads();
    if (node >= NN) return;
    float acc = 0.f;
#pragma unroll
    for (int k = 0; k < 64; k++) acc += sX[r * 64 + k] * sW[k * 64 + u];
    Y[node * 64 + u] = acc;
}

// MLP (64->64 tanh ->32 tanh ->1) + mean-pool accumulation
__global__ void k_mlp_pool(const float* __restrict__ X, const int* __restrict__ batch,
                           const float* __restrict__ W1, const float* __restrict__ b1,
                           const float* __restrict__ W2, const float* __restrict__ b2,
                           const float* __restrict__ W3, const float* __restrict__ b3,
                           float* __restrict__ sums, float* __restrict__ cnts) {
    __shared__ float sW1[64 * 64];
    __shared__ float sW2[64 * 32];
    __shared__ float sW3[32], sb1[64], sb2[32];
    __shared__ float sX[4 * 64];
    __shared__ float sY1[4 * 64];
    __shared__ float sY2[4 * 32];
    int t = threadIdx.x;
    for (int i = t; i < 64 * 64; i += 256) sW1[i] = W1[i];
    for (int i = t; i < 64 * 32; i += 256) sW2[i] = W2[i];
    if (t < 32) { sW3[t] = W3[t]; sb2[t] = b2[t]; }
    if (t < 64) sb1[t] = b1[t];
    int r = t >> 6, u = t & 63;
    int node = blockIdx.x * 4 + r;
    sX[t] = node < NN ? X[node * 64 + u] : 0.f;
    __syncthreads();
    float acc = sb1[u];
#pragma unroll
    for (int k = 0; k < 64; k++) acc += sX[r * 64 + k] * sW1[k * 64 + u];
    sY1[t] = tanhf(acc);
    __syncthreads();
    if (u < 32) {
        float a2 = sb2[u];
#pragma unroll
        for (int k = 0; k < 64; k++) a2 += sY1[r * 64 + k] * sW2[k * 32 + u];
        sY2[r * 32 + u] = tanhf(a2);
    }
    __syncthreads();
    float p = (u < 32) ? sY2[r * 32 + u] * sW3[u] : 0.f;
    p = wsum64(p);
    if (u == 0 && node < NN) {
        float v = p + b3[0];
        int g = batch[node];
        atomicAdd(&sums[g], v);
        atomicAdd(&cnts[g], 1.f);
    }
}

__global__ void k_zero(float* __restrict__ p, int n) {
    int i = blockIdx.x * 256 + threadIdx.x;
    if (i < n) p[i] = 0.f;
}

// pool layout: [sa(NG), ca(NG), sb(NG), cb(NG)]
__global__ void k_final(const float* __restrict__ pool, float* __restrict__ out) {
    int g = blockIdx.x * 256 + threadIdx.x;
    if (g >= NG) return;
    float ua = pool[g] / fmaxf(pool[NG + g], 1.f);
    float ub = pool[2 * NG + g] / fmaxf(pool[3 * NG + g], 1.f);
    float z = ub - ua;
    out[g] = 1.f / (1.f + expf(-z));
}

struct Params {
    const float *Wg, *avs, *avd, *bg, *Wgcn, *bgcn, *W1, *b1, *W2, *b2, *W3, *b3;
};

static void run_branch(const float* x, const int* ei, const int* batch, const Params& P,
                       float* A, float* B, float* als, float* ald, float* dinv,
                       int* cnt, int* rowptr, int* cursor, int* csr_src,
                       float* psum, float* pcnt, hipStream_t st) {
    dim3 blk(256);
    const int gNode4 = (NN + 3) / 4;
    const int gN = (NN + 255) / 256;
    const int gE = (NET + 255) / 256;

    // CSR build
    k_zero_i<<<gN, blk, 0, st>>>(cnt, NN);
    k_deg<<<gE, blk, 0, st>>>(ei, cnt);
    k_scan<<<1, 1024, 0, st>>>(cnt, rowptr, cursor);
    k_scatter<<<gE, blk, 0, st>>>(ei, cursor, csr_src);
    k_dinv<<<gN, blk, 0, st>>>(rowptr, dinv);

    // GAT
    k_gat_input<<<gNode4, blk, 0, st>>>(x, P.Wg, P.avs, P.avd, A, als, ald);
    k_gat_csr<<<gNode4, blk, 0, st>>>(rowptr, csr_src, als, ald, A, P.bg, B);

    // 2x GCN
    for (int l = 0; l < 2; l++) {
        k_lin64<<<gNode4, blk, 0, st>>>(B, P.Wgcn + l * 64 * 64, A);
        k_gcn_csr<<<gNode4, blk, 0, st>>>(rowptr, csr_src, dinv, A, P.bgcn + l * 64, B);
    }

    // MLP + pool
    k_mlp_pool<<<gNode4, blk, 0, st>>>(B, batch, P.W1, P.b1, P.W2, P.b2, P.W3, P.b3,
                                       psum, pcnt);
}

extern "C" void kernel_launch(void* const* d_in, const int* in_sizes, int n_in,
                              void* d_out, int out_size, void* d_ws, size_t ws_size,
                              hipStream_t stream) {
    const float* x_a = (const float*)d_in[0];
    const float* x_b = (const float*)d_in[1];
    const int* ei_a = (const int*)d_in[2];
    const int* ei_b = (const int*)d_in[3];
    const int* batch_a = (const int*)d_in[4];
    const int* batch_b = (const int*)d_in[5];
    Params P;
    P.Wg  = (const float*)d_in[6];
    P.avs = (const float*)d_in[7];
    P.avd = (const float*)d_in[8];
    P.bg  = (const float*)d_in[9];
    P.Wgcn = (const float*)d_in[10];
    P.bgcn = (const float*)d_in[11];
    P.W1 = (const float*)d_in[12];
    P.b1 = (const float*)d_in[13];
    P.W2 = (const float*)d_in[14];
    P.b2 = (const float*)d_in[15];
    P.W3 = (const float*)d_in[16];
    P.b3 = (const float*)d_in[17];

    float* ws = (float*)d_ws;
    float* A    = ws;                 // NN*64
    float* B    = A + NN * 64;        // NN*64
    float* als  = B + NN * 64;        // NN
    float* ald  = als + NN;           // NN
    float* dinv = ald + NN;           // NN
    float* pool = dinv + NN;          // 4*NG
    int* cnt     = (int*)(pool + 4 * NG);   // NN
    int* rowptr  = cnt + NN;                // NN+1
    int* cursor  = rowptr + NN + 1;         // NN
    int* csr_src = cursor + NN;             // NET

    k_zero<<<(4 * NG + 255) / 256, 256, 0, stream>>>(pool, 4 * NG);
    run_branch(x_a, ei_a, batch_a, P, A, B, als, ald, dinv,
               cnt, rowptr, cursor, csr_src, pool, pool + NG, stream);
    run_branch(x_b, ei_b, batch_b, P, A, B, als, ald, dinv,
               cnt, rowptr, cursor, csr_src, pool + 2 * NG, pool + 3 * NG, stream);
    k_final<<<(NG + 255) / 256, 256, 0, stream>>>(pool, (float*)d_out);
}

// Round 3
// 1384.134 us; speedup vs baseline: 1.4945x; 1.0372x over previous
//
#include <hip/hip_runtime.h>
#include <math.h>

#define NN 50000
#define NE 800000
#define NG 512
#define NET (NE + NN)   // edges + self loops

__device__ __forceinline__ float wsum64(float v) {
#pragma unroll
    for (int o = 32; o > 0; o >>= 1) v += __shfl_down(v, o, 64);
    return v;
}

// ---------------- CSR build ----------------

__global__ void k_zero_i(int* __restrict__ p, int n) {
    int i = blockIdx.x * 256 + threadIdx.x;
    if (i < n) p[i] = 0;
}

__global__ void k_deg(const int* __restrict__ ei, int* __restrict__ cnt) {
    int e = blockIdx.x * 256 + threadIdx.x;
    if (e >= NET) return;
    int d = (e < NE) ? ei[NE + e] : (e - NE);
    atomicAdd(&cnt[d], 1);
}

// exclusive scan of cnt[NN] -> rowptr[NN+1], cursor[NN]
// single block, 1024 threads, each thread owns a contiguous chunk
__global__ void k_scan(const int* __restrict__ cnt, int* __restrict__ rowptr,
                       int* __restrict__ cursor) {
    __shared__ int s[1024];
    int t = threadIdx.x;
    const int C = (NN + 1023) / 1024;  // 49
    int beg = t * C, end = beg + C < NN ? beg + C : NN;
    int sum = 0;
    for (int i = beg; i < end; i++) sum += cnt[i];
    s[t] = sum;
    __syncthreads();
    for (int o = 1; o < 1024; o <<= 1) {
        int add = (t >= o) ? s[t - o] : 0;
        __syncthreads();
        s[t] += add;
        __syncthreads();
    }
    int run = s[t] - sum;   // exclusive prefix of this chunk
    for (int i = beg; i < end; i++) {
        rowptr[i] = run; cursor[i] = run; run += cnt[i];
    }
    if (t == 1023) rowptr[NN] = run;
}

__global__ void k_scatter(const int* __restrict__ ei, int* __restrict__ cursor,
                          int* __restrict__ csr_src) {
    int e = blockIdx.x * 256 + threadIdx.x;
    if (e >= NET) return;
    int s, d;
    if (e < NE) { s = ei[e]; d = ei[NE + e]; } else { s = d = e - NE; }
    int pos = atomicAdd(&cursor[d], 1);
    csr_src[pos] = s;
}

__global__ void k_dinv(const int* __restrict__ rowptr, float* __restrict__ dinv) {
    int i = blockIdx.x * 256 + threadIdx.x;
    if (i < NN) {
        int dg = rowptr[i + 1] - rowptr[i];
        dinv[i] = dg > 0 ? rsqrtf((float)dg) : 0.f;
    }
}

// ---------------- node-level kernels ----------------

// A = x @ W_gat  ([NN,9]@[9,64]); alpha_s = A@a_src, alpha_d = A@a_dst
__global__ void k_gat_input(const float* __restrict__ x, const float* __restrict__ Wg,
                            const float* __restrict__ avs, const float* __restrict__ avd,
                            float* __restrict__ A, float* __restrict__ als, float* __restrict__ ald) {
    __shared__ float sW[9 * 64];
    __shared__ float sas[64], sad[64];
    int t = threadIdx.x;
    for (int i = t; i < 9 * 64; i += 256) sW[i] = Wg[i];
    if (t < 64) { sas[t] = avs[t]; sad[t] = avd[t]; }
    __syncthreads();
    int node = blockIdx.x * 4 + (t >> 6);
    int u = t & 63;
    if (node >= NN) return;
    float h = 0.f;
#pragma unroll
    for (int f = 0; f < 9; f++) h += x[node * 9 + f] * sW[f * 64 + u];
    A[node * 64 + u] = h;
    float ps = wsum64(h * sas[u]);
    float pd = wsum64(h * sad[u]);
    if (u == 0) { als[node] = ps; ald[node] = pd; }
}

// GAT: per-dst wave; softmax over incoming edges + aggregate + bias + tanh
__global__ void k_gat_csr(const int* __restrict__ rowptr, const int* __restrict__ csr_src,
                          const float* __restrict__ als, const float* __restrict__ ald,
                          const float* __restrict__ A, const float* __restrict__ bias,
                          float* __restrict__ B) {
    int d = blockIdx.x * 4 + (threadIdx.x >> 6);
    int u = threadIdx.x & 63;
    if (d >= NN) return;
    int beg = rowptr[d], end = rowptr[d + 1];
    float ad = ald[d];
    float mx = -INFINITY;
    for (int i = beg + u; i < end; i += 64) {
        float v = als[csr_src[i]] + ad;
        v = v >= 0.f ? v : 0.2f * v;
        mx = fmaxf(mx, v);
    }
#pragma unroll
    for (int o = 32; o > 0; o >>= 1) mx = fmaxf(mx, __shfl_down(mx, o, 64));
    mx = __shfl(mx, 0, 64);
    float sm = 0.f;
    for (int i = beg + u; i < end; i += 64) {
        float v = als[csr_src[i]] + ad;
        v = v >= 0.f ? v : 0.2f * v;
        sm += expf(v - mx);
    }
    sm = wsum64(sm);
    sm = __shfl(sm, 0, 64);
    float inv = 1.f / sm;
    float acc = bias[u];
    for (int i = beg; i < end; i++) {
        int s = csr_src[i];
        float v = als[s] + ad;
        v = v >= 0.f ? v : 0.2f * v;
        acc += A[s * 64 + u] * (expf(v - mx) * inv);
    }
    B[d * 64 + u] = tanhf(acc);
}

// GCN: per-dst wave; aggregate + bias + tanh
__global__ void k_gcn_csr(const int* __restrict__ rowptr, const int* __restrict__ csr_src,
                          const float* __restrict__ dinv, const float* __restrict__ A,
                          const float* __restrict__ bias, float* __restrict__ B) {
    int d = blockIdx.x * 4 + (threadIdx.x >> 6);
    int u = threadIdx.x & 63;
    if (d >= NN) return;
    int beg = rowptr[d], end = rowptr[d + 1];
    float dd = dinv[d];
    float acc = bias[u];
    for (int i = beg; i < end; i++) {
        int s = csr_src[i];
        acc += A[s * 64 + u] * (dinv[s] * dd);
    }
    B[d * 64 + u] = tanhf(acc);
}

// Y = X @ W  ([NN,64]@[64,64]) — persistent: weights loaded once per block
__global__ void k_lin64(const float* __restrict__ X, const float* __restrict__ W,
                        float* __restrict__ Y) {
    __shared__ float sW[64 * 64];
    __shared__ float sX[4 * 64];
    int t = threadIdx.x;
    for (int i = t; i < 64 * 64; i += 256) sW[i] = W[i];
    __syncthreads();
    int r = t >> 6, u = t & 63;
    for (int base = blockIdx.x * 4; base < NN; base += gridDim.x * 4) {
        int node = base + r;
        sX[t] = node < NN ? X[node * 64 + u] : 0.f;
        __syncthreads();
        float acc = 0.f;
#pragma unroll
        for (int k = 0; k < 64; k++) acc += sX[r * 64 + k] * sW[k * 64 + u];
        if (node < NN) Y[node * 64 + u] = acc;
        __syncthreads();
    }
}

// MLP (64->64 tanh ->32 tanh ->1) + mean-pool accumulation — persistent
__global__ void k_mlp_pool(const float* __restrict__ X, const int* __restrict__ batch,
                           const float* __restrict__ W1, const float* __restrict__ b1,
                           const float* __restrict__ W2, const float* __restrict__ b2,
                           const float* __restrict__ W3, const float* __restrict__ b3,
                           float* __restrict__ sums, float* __restrict__ cnts) {
    __shared__ float sW1[64 * 64];
    __shared__ float sW2[64 * 32];
    __shared__ float sW3[32], sb1[64], sb2[32];
    __shared__ float sX[4 * 64];
    __shared__ float sY1[4 * 64];
    __shared__ float sY2[4 * 32];
    int t = threadIdx.x;
    for (int i = t; i < 64 * 64; i += 256) sW1[i] = W1[i];
    for (int i = t; i < 64 * 32; i += 256) sW2[i] = W2[i];
    if (t < 32) { sW3[t] = W3[t]; sb2[t] = b2[t]; }
    if (t < 64) sb1[t] = b1[t];
    __syncthreads();
    int r = t >> 6, u = t & 63;
    float bb3 = b3[0];
    for (int base = blockIdx.x * 4; base < NN; base += gridDim.x * 4) {
        int node = base + r;
        sX[t] = node < NN ? X[node * 64 + u] : 0.f;
        __syncthreads();
        float acc = sb1[u];
#pragma unroll
        for (int k = 0; k < 64; k++) acc += sX[r * 64 + k] * sW1[k * 64 + u];
        sY1[t] = tanhf(acc);
        __syncthreads();
        if (u < 32) {
            float a2 = sb2[u];
#pragma unroll
            for (int k = 0; k < 64; k++) a2 += sY1[r * 64 + k] * sW2[k * 32 + u];
            sY2[r * 32 + u] = tanhf(a2);
        }
        __syncthreads();
        float p = (u < 32) ? sY2[r * 32 + u] * sW3[u] : 0.f;
        p = wsum64(p);
        if (u == 0 && node < NN) {
            int g = batch[node];
            atomicAdd(&sums[g], p + bb3);
            atomicAdd(&cnts[g], 1.f);
        }
        __syncthreads();
    }
}

__global__ void k_zero(float* __restrict__ p, int n) {
    int i = blockIdx.x * 256 + threadIdx.x;
    if (i < n) p[i] = 0.f;
}

// pool layout: [sa(NG), ca(NG), sb(NG), cb(NG)]
__global__ void k_final(const float* __restrict__ pool, float* __restrict__ out) {
    int g = blockIdx.x * 256 + threadIdx.x;
    if (g >= NG) return;
    float ua = pool[g] / fmaxf(pool[NG + g], 1.f);
    float ub = pool[2 * NG + g] / fmaxf(pool[3 * NG + g], 1.f);
    float z = ub - ua;
    out[g] = 1.f / (1.f + expf(-z));
}

struct Params {
    const float *Wg, *avs, *avd, *bg, *Wgcn, *bgcn, *W1, *b1, *W2, *b2, *W3, *b3;
};

static void run_branch(const float* x, const int* ei, const int* batch, const Params& P,
                       float* A, float* B, float* als, float* ald, float* dinv,
                       int* cnt, int* rowptr, int* cursor, int* csr_src,
                       float* psum, float* pcnt, hipStream_t st) {
    dim3 blk(256);
    const int gNode4 = (NN + 3) / 4;
    const int gN = (NN + 255) / 256;
    const int gE = (NET + 255) / 256;
    const int gPersist = 512;   // persistent blocks: weights loaded once

    // CSR build
    k_zero_i<<<gN, blk, 0, st>>>(cnt, NN);
    k_deg<<<gE, blk, 0, st>>>(ei, cnt);
    k_scan<<<1, 1024, 0, st>>>(cnt, rowptr, cursor);
    k_scatter<<<gE, blk, 0, st>>>(ei, cursor, csr_src);
    k_dinv<<<gN, blk, 0, st>>>(rowptr, dinv);

    // GAT
    k_gat_input<<<gNode4, blk, 0, st>>>(x, P.Wg, P.avs, P.avd, A, als, ald);
    k_gat_csr<<<gNode4, blk, 0, st>>>(rowptr, csr_src, als, ald, A, P.bg, B);

    // 2x GCN
    for (int l = 0; l < 2; l++) {
        k_lin64<<<gPersist, blk, 0, st>>>(B, P.Wgcn + l * 64 * 64, A);
        k_gcn_csr<<<gNode4, blk, 0, st>>>(rowptr, csr_src, dinv, A, P.bgcn + l * 64, B);
    }

    // MLP + pool
    k_mlp_pool<<<gPersist, blk, 0, st>>>(B, batch, P.W1, P.b1, P.W2, P.b2, P.W3, P.b3,
                                         psum, pcnt);
}

extern "C" void kernel_launch(void* const* d_in, const int* in_sizes, int n_in,
                              void* d_out, int out_size, void* d_ws, size_t ws_size,
                              hipStream_t stream) {
    const float* x_a = (const float*)d_in[0];
    const float* x_b = (const float*)d_in[1];
    const int* ei_a = (const int*)d_in[2];
    const int* ei_b = (const int*)d_in[3];
    const int* batch_a = (const int*)d_in[4];
    const int* batch_b = (const int*)d_in[5];
    Params P;
    P.Wg  = (const float*)d_in[6];
    P.avs = (const float*)d_in[7];
    P.avd = (const float*)d_in[8];
    P.bg  = (const float*)d_in[9];
    P.Wgcn = (const float*)d_in[10];
    P.bgcn = (const float*)d_in[11];
    P.W1 = (const float*)d_in[12];
    P.b1 = (const float*)d_in[13];
    P.W2 = (const float*)d_in[14];
    P.b2 = (const float*)d_in[15];
    P.W3 = (const float*)d_in[16];
    P.b3 = (const float*)d_in[17];

    float* ws = (float*)d_ws;
    float* A    = ws;                 // NN*64
    float* B    = A + NN * 64;        // NN*64
    float* als  = B + NN * 64;        // NN
    float* ald  = als + NN;           // NN
    float* dinv = ald + NN;           // NN
    float* pool = dinv + NN;          // 4*NG
    int* cnt     = (int*)(pool + 4 * NG);   // NN
    int* rowptr  = cnt + NN;                // NN+1
    int* cursor  = rowptr + NN + 1;         // NN
    int* csr_src = cursor + NN;             // NET

    k_zero<<<(4 * NG + 255) / 256, 256, 0, stream>>>(pool, 4 * NG);
    run_branch(x_a, ei_a, batch_a, P, A, B, als, ald, dinv,
               cnt, rowptr, cursor, csr_src, pool, pool + NG, stream);
    run_branch(x_b, ei_b, batch_b, P, A, B, als, ald, dinv,
               cnt, rowptr, cursor, csr_src, pool + 2 * NG, pool + 3 * NG, stream);
    k_final<<<(NG + 255) / 256, 256, 0, stream>>>(pool, (float*)d_out);
}

// Round 4
// 1010.328 us; speedup vs baseline: 2.0475x; 1.3700x over previous
//
#include <hip/hip_runtime.h>
#include <math.h>

#define NN 50000
#define NE 800000
#define NG 512
#define NET (NE + NN)   // edges + self loops

__device__ __forceinline__ float wsum64(float v) {
#pragma unroll
    for (int o = 32; o > 0; o >>= 1) v += __shfl_down(v, o, 64);
    return v;
}

// tanh(x) = 1 - 2/(exp(2x)+1); v_exp/v_rcp accuracy ~1e-6, fine vs 1e-2 threshold
__device__ __forceinline__ float fast_tanh(float x) {
    return 1.f - 2.f / (__expf(2.f * x) + 1.f);
}

// ---------------- CSR build (both branches in one launch set) ----------------

__global__ void k_zero_i(int* __restrict__ p, int n) {
    int i = blockIdx.x * 256 + threadIdx.x;
    if (i < n) p[i] = 0;
}

// grid covers 2*NET threads; branch = high half
__global__ void k_deg(const int* __restrict__ eia, const int* __restrict__ eib,
                      int* __restrict__ cnt2) {
    int e = blockIdx.x * 256 + threadIdx.x;
    if (e >= 2 * NET) return;
    int br = e >= NET;
    int el = e - br * NET;
    const int* ei = br ? eib : eia;
    int d = (el < NE) ? ei[NE + el] : (el - NE);
    atomicAdd(&cnt2[br * NN + d], 1);
}

// 2 blocks (one per branch), 1024 threads; chunk-serial scan.
// Also emits dinv (degree includes self loop) and zeroes the pool bins.
__global__ void k_scan(const int* __restrict__ cnt2, int* __restrict__ rowptr2,
                       int* __restrict__ cursor2, float* __restrict__ dinv2,
                       float* __restrict__ pool) {
    __shared__ int s[1024];
    int b = blockIdx.x, t = threadIdx.x;
    if (b == 0) { pool[t] = 0.f; pool[1024 + t] = 0.f; }
    const int* cnt = cnt2 + b * NN;
    int* rowptr = rowptr2 + b * (NN + 1);
    int* cursor = cursor2 + b * NN;
    float* dinv = dinv2 + b * NN;
    const int C = (NN + 1023) / 1024;  // 49
    int beg = t * C, end = beg + C < NN ? beg + C : NN;
    int sum = 0;
    for (int i = beg; i < end; i++) sum += cnt[i];
    s[t] = sum;
    __syncthreads();
    for (int o = 1; o < 1024; o <<= 1) {
        int add = (t >= o) ? s[t - o] : 0;
        __syncthreads();
        s[t] += add;
        __syncthreads();
    }
    int run = s[t] - sum;
    for (int i = beg; i < end; i++) {
        int c = cnt[i];
        rowptr[i] = run; cursor[i] = run; run += c;
        dinv[i] = c > 0 ? rsqrtf((float)c) : 0.f;
    }
    if (t == 1023) rowptr[NN] = run;
}

__global__ void k_scatter(const int* __restrict__ eia, const int* __restrict__ eib,
                          int* __restrict__ cursor2, int* __restrict__ csr2) {
    int e = blockIdx.x * 256 + threadIdx.x;
    if (e >= 2 * NET) return;
    int br = e >= NET;
    int el = e - br * NET;
    const int* ei = br ? eib : eia;
    int s, d;
    if (el < NE) { s = ei[el]; d = ei[NE + el]; } else { s = d = el - NE; }
    int pos = atomicAdd(&cursor2[br * NN + d], 1);
    csr2[br * NET + pos] = s;
}

// ---------------- node-level kernels ----------------

// A = x @ W_gat  ([NN,9]@[9,64]); alpha_s = A@a_src, alpha_d = A@a_dst
__global__ void k_gat_input(const float* __restrict__ x, const float* __restrict__ Wg,
                            const float* __restrict__ avs, const float* __restrict__ avd,
                            float* __restrict__ A, float* __restrict__ als, float* __restrict__ ald) {
    __shared__ float sW[9 * 64];
    __shared__ float sas[64], sad[64];
    int t = threadIdx.x;
    for (int i = t; i < 9 * 64; i += 256) sW[i] = Wg[i];
    if (t < 64) { sas[t] = avs[t]; sad[t] = avd[t]; }
    __syncthreads();
    int node = blockIdx.x * 4 + (t >> 6);
    int u = t & 63;
    if (node >= NN) return;
    float h = 0.f;
#pragma unroll
    for (int f = 0; f < 9; f++) h += x[node * 9 + f] * sW[f * 64 + u];
    A[node * 64 + u] = h;
    float ps = wsum64(h * sas[u]);
    float pd = wsum64(h * sad[u]);
    if (u == 0) { als[node] = ps; ald[node] = pd; }
}

// GAT: per-dst wave; softmax over incoming edges + aggregate + bias + tanh
__global__ void k_gat_csr(const int* __restrict__ rowptr, const int* __restrict__ csr_src,
                          const float* __restrict__ als, const float* __restrict__ ald,
                          const float* __restrict__ A, const float* __restrict__ bias,
                          float* __restrict__ B) {
    int d = blockIdx.x * 4 + (threadIdx.x >> 6);
    int u = threadIdx.x & 63;
    if (d >= NN) return;
    int beg = rowptr[d], end = rowptr[d + 1];
    float ad = ald[d];
    // max (lanes parallel over edges); leaky_relu(v) == max(v, 0.2v)
    float mx = -INFINITY;
    for (int i = beg + u; i < end; i += 64) {
        float v = als[csr_src[i]] + ad;
        mx = fmaxf(mx, fmaxf(v, 0.2f * v));
    }
#pragma unroll
    for (int o = 32; o > 0; o >>= 1) mx = fmaxf(mx, __shfl_down(mx, o, 64));
    mx = __shfl(mx, 0, 64);
    // exp-sum
    float sm = 0.f;
    for (int i = beg + u; i < end; i += 64) {
        float v = als[csr_src[i]] + ad;
        sm += __expf(fmaxf(v, 0.2f * v) - mx);
    }
    sm = wsum64(sm);
    sm = __shfl(sm, 0, 64);
    float inv = 1.f / sm;
    // aggregate (lanes parallel over features), unroll 4 for MLP
    float acc = 0.f;
    int i = beg;
    for (; i + 4 <= end; i += 4) {
        int s0 = csr_src[i], s1 = csr_src[i + 1], s2 = csr_src[i + 2], s3 = csr_src[i + 3];
        float v0 = als[s0] + ad, v1 = als[s1] + ad, v2 = als[s2] + ad, v3 = als[s3] + ad;
        float w0 = __expf(fmaxf(v0, 0.2f * v0) - mx);
        float w1 = __expf(fmaxf(v1, 0.2f * v1) - mx);
        float w2 = __expf(fmaxf(v2, 0.2f * v2) - mx);
        float w3 = __expf(fmaxf(v3, 0.2f * v3) - mx);
        acc += A[s0 * 64 + u] * w0 + A[s1 * 64 + u] * w1
             + A[s2 * 64 + u] * w2 + A[s3 * 64 + u] * w3;
    }
    for (; i < end; i++) {
        int s = csr_src[i];
        float v = als[s] + ad;
        acc += A[s * 64 + u] * __expf(fmaxf(v, 0.2f * v) - mx);
    }
    B[d * 64 + u] = fast_tanh(acc * inv + bias[u]);
}

// GCN fused: out = tanh( (dinv[d] * sum_s dinv[s]*Bin[s]) @ W + b )
// 32 nodes / 256-thread block; W staged in LDS once per block.
__global__ __launch_bounds__(256) void k_gcn_fused(
        const int* __restrict__ rowptr, const int* __restrict__ csr_src,
        const float* __restrict__ dinv, const float* __restrict__ Bin,
        const float* __restrict__ W, const float* __restrict__ bias,
        float* __restrict__ Bout) {
    __shared__ float sW[64 * 64];
    __shared__ float sB[64];
    int t = threadIdx.x;
#pragma unroll
    for (int i = t; i < 64 * 64; i += 256) sW[i] = W[i];
    if (t < 64) sB[t] = bias[t];
    __syncthreads();
    int w = t >> 6, u = t & 63;
    int base = blockIdx.x * 32;
    for (int j = 0; j < 8; j++) {
        int d = base + w + 4 * j;
        if (d >= NN) continue;
        int beg = rowptr[d], end = rowptr[d + 1];
        float acc = 0.f;
        int i = beg;
        for (; i + 4 <= end; i += 4) {
            int s0 = csr_src[i], s1 = csr_src[i + 1], s2 = csr_src[i + 2], s3 = csr_src[i + 3];
            float w0 = dinv[s0], w1 = dinv[s1], w2 = dinv[s2], w3 = dinv[s3];
            acc += Bin[s0 * 64 + u] * w0 + Bin[s1 * 64 + u] * w1
                 + Bin[s2 * 64 + u] * w2 + Bin[s3 * 64 + u] * w3;
        }
        for (; i < end; i++) { int s = csr_src[i]; acc += Bin[s * 64 + u] * dinv[s]; }
        float h = acc * dinv[d];
        float y = sB[u];
#pragma unroll
        for (int k = 0; k < 64; k++) y += __shfl(h, k, 64) * sW[k * 64 + u];
        Bout[d * 64 + u] = fast_tanh(y);
    }
}

// MLP (64->64 tanh ->32 tanh ->1) + mean-pool. Lane = node; weights via
// wave-uniform (scalar) loads; no LDS, no barriers. Fully unrolled.
__global__ __launch_bounds__(64) void k_mlp_pool(
        const float* __restrict__ X, const int* __restrict__ batch,
        const float* __restrict__ W1, const float* __restrict__ b1,
        const float* __restrict__ W2, const float* __restrict__ b2,
        const float* __restrict__ W3, const float* __restrict__ b3,
        float* __restrict__ sums, float* __restrict__ cnts) {
    int node = blockIdx.x * 64 + threadIdx.x;
    if (node >= NN) return;
    float x[64];
    const float4* Xv = (const float4*)(X + node * 64);
#pragma unroll
    for (int q = 0; q < 16; q++) {
        float4 v = Xv[q];
        x[4 * q] = v.x; x[4 * q + 1] = v.y; x[4 * q + 2] = v.z; x[4 * q + 3] = v.w;
    }
    float y1[64];
#pragma unroll
    for (int j = 0; j < 64; j++) y1[j] = b1[j];
#pragma unroll
    for (int k = 0; k < 64; k++) {
        float xk = x[k];
        const float* Wr = W1 + k * 64;
#pragma unroll
        for (int j = 0; j < 64; j++) y1[j] += xk * Wr[j];
    }
#pragma unroll
    for (int j = 0; j < 64; j++) y1[j] = fast_tanh(y1[j]);
    float y2[32];
#pragma unroll
    for (int j = 0; j < 32; j++) y2[j] = b2[j];
#pragma unroll
    for (int k = 0; k < 64; k++) {
        float hk = y1[k];
        const float* Wr = W2 + k * 32;
#pragma unroll
        for (int j = 0; j < 32; j++) y2[j] += hk * Wr[j];
    }
    float o = b3[0];
#pragma unroll
    for (int j = 0; j < 32; j++) o += fast_tanh(y2[j]) * W3[j];
    int g = batch[node];
    atomicAdd(&sums[g], o);
    atomicAdd(&cnts[g], 1.f);
}

// pool layout: [sa(NG), ca(NG), sb(NG), cb(NG)]
__global__ void k_final(const float* __restrict__ pool, float* __restrict__ out) {
    int g = blockIdx.x * 256 + threadIdx.x;
    if (g >= NG) return;
    float ua = pool[g] / fmaxf(pool[NG + g], 1.f);
    float ub = pool[2 * NG + g] / fmaxf(pool[3 * NG + g], 1.f);
    float z = ub - ua;
    out[g] = 1.f / (1.f + __expf(-z));
}

struct Params {
    const float *Wg, *avs, *avd, *bg, *Wgcn, *bgcn, *W1, *b1, *W2, *b2, *W3, *b3;
};

static void run_branch(const float* x, const int* batch, const Params& P,
                       const int* rowptr, const int* csr, const float* dinv,
                       float* A, float* B, float* als, float* ald,
                       float* psum, float* pcnt, hipStream_t st) {
    dim3 blk(256);
    const int gNode4 = (NN + 3) / 4;
    const int gGcn = (NN + 31) / 32;
    const int gMlp = (NN + 63) / 64;

    k_gat_input<<<gNode4, blk, 0, st>>>(x, P.Wg, P.avs, P.avd, A, als, ald);
    k_gat_csr<<<gNode4, blk, 0, st>>>(rowptr, csr, als, ald, A, P.bg, B);
    k_gcn_fused<<<gGcn, blk, 0, st>>>(rowptr, csr, dinv, B, P.Wgcn, P.bgcn, A);
    k_gcn_fused<<<gGcn, blk, 0, st>>>(rowptr, csr, dinv, A, P.Wgcn + 64 * 64, P.bgcn + 64, B);
    k_mlp_pool<<<gMlp, dim3(64), 0, st>>>(B, batch, P.W1, P.b1, P.W2, P.b2, P.W3, P.b3,
                                          psum, pcnt);
}

extern "C" void kernel_launch(void* const* d_in, const int* in_sizes, int n_in,
                              void* d_out, int out_size, void* d_ws, size_t ws_size,
                              hipStream_t stream) {
    const float* x_a = (const float*)d_in[0];
    const float* x_b = (const float*)d_in[1];
    const int* ei_a = (const int*)d_in[2];
    const int* ei_b = (const int*)d_in[3];
    const int* batch_a = (const int*)d_in[4];
    const int* batch_b = (const int*)d_in[5];
    Params P;
    P.Wg  = (const float*)d_in[6];
    P.avs = (const float*)d_in[7];
    P.avd = (const float*)d_in[8];
    P.bg  = (const float*)d_in[9];
    P.Wgcn = (const float*)d_in[10];
    P.bgcn = (const float*)d_in[11];
    P.W1 = (const float*)d_in[12];
    P.b1 = (const float*)d_in[13];
    P.W2 = (const float*)d_in[14];
    P.b2 = (const float*)d_in[15];
    P.W3 = (const float*)d_in[16];
    P.b3 = (const float*)d_in[17];

    float* ws = (float*)d_ws;
    float* A     = ws;                  // NN*64
    float* B     = A + NN * 64;         // NN*64
    float* als   = B + NN * 64;         // NN
    float* ald   = als + NN;            // NN
    float* dinv2 = ald + NN;            // 2*NN
    float* pool  = dinv2 + 2 * NN;      // 4*NG
    int* cnt2    = (int*)(pool + 4 * NG);   // 2*NN
    int* rowptr2 = cnt2 + 2 * NN;           // 2*(NN+1)
    int* cursor2 = rowptr2 + 2 * (NN + 1);  // 2*NN
    int* csr2    = cursor2 + 2 * NN;        // 2*NET

    dim3 blk(256);
    const int gE2 = (2 * NET + 255) / 256;

    // CSR build for both branches
    k_zero_i<<<(2 * NN + 255) / 256, blk, 0, stream>>>(cnt2, 2 * NN);
    k_deg<<<gE2, blk, 0, stream>>>(ei_a, ei_b, cnt2);
    k_scan<<<2, 1024, 0, stream>>>(cnt2, rowptr2, cursor2, dinv2, pool);
    k_scatter<<<gE2, blk, 0, stream>>>(ei_a, ei_b, cursor2, csr2);

    run_branch(x_a, batch_a, P, rowptr2, csr2, dinv2,
               A, B, als, ald, pool, pool + NG, stream);
    run_branch(x_b, batch_b, P, rowptr2 + (NN + 1), csr2 + NET, dinv2 + NN,
               A, B, als, ald, pool + 2 * NG, pool + 3 * NG, stream);
    k_final<<<(NG + 255) / 256, blk, 0, stream>>>(pool, (float*)d_out);
}